// Round 2
// baseline (449.402 us; speedup 1.0000x reference)
//
#include <hip/hip_runtime.h>
#include <hip/hip_bf16.h>
#include <stdint.h>

#define D_MODEL    512
#define S_LEN      16384
#define B_SZ       8
#define N_GRIDS    32
#define N_PAIRS    16
#define MAX_PIXELS 900

// 8 elements per thread per batch -> 64 chunks per D-row; 16384*64 = 1,048,576 threads.
#define CHUNKS_PER_ROW (D_MODEL / 8)
#define TOTAL_CHUNKS   (S_LEN * CHUNKS_PER_ROW)

__device__ __forceinline__ float bf16u_to_f32(uint32_t lo16) {
    union { uint32_t u; float f; } c;
    c.u = lo16 << 16;
    return c.f;
}

__device__ __forceinline__ uint16_t f32_to_bf16_rne(float f) {
    union { float f; uint32_t u; } c; c.f = f;
    uint32_t u = c.u;
    u += 0x7FFFu + ((u >> 16) & 1u);   // round-to-nearest-even
    return (uint16_t)(u >> 16);
}

__device__ __forceinline__ uint32_t pack2_bf16(float lo, float hi) {
    return (uint32_t)f32_to_bf16_rne(lo) | ((uint32_t)f32_to_bf16_rne(hi) << 16);
}

__global__ __launch_bounds__(256) void PositionalEncoding_30915174597069_kernel(
    const void* __restrict__ x,
    const void* __restrict__ pixels_pe,
    const void* __restrict__ grids_pe,
    const void* __restrict__ pairs_pe,
    const int* __restrict__ grid_starts,
    const int* __restrict__ grid_lengths,
    const int* __restrict__ pair_starts,
    const int* __restrict__ pair_lengths,
    void* __restrict__ out)
{
    const int chunk = blockIdx.x * blockDim.x + threadIdx.x;
    if (chunk >= TOTAL_CHUNKS) return;

    const int s = chunk >> 6;           // wave-uniform: 64 lanes share one row
    const int d = (chunk & 63) << 3;    // element offset within row

    // searchsorted(starts, s, 'right') - 1 : largest i with starts[i] <= s.
    // starts[0] == 0 so index 0 is a valid floor. Branchless binary search.
    int gid = 0;
    #pragma unroll
    for (int sh = 4; sh >= 0; --sh) {
        int cand = gid + (1 << sh);
        if (cand < N_GRIDS && grid_starts[cand] <= s) gid = cand;
    }
    const int goff   = s - grid_starts[gid];
    const bool gmask = goff < grid_lengths[gid];
    const int pixrow = min(goff, MAX_PIXELS - 1);   // clip (goff >= 0 by construction)

    int pid = 0;
    #pragma unroll
    for (int sh = 3; sh >= 0; --sh) {
        int cand = pid + (1 << sh);
        if (cand < N_PAIRS && pair_starts[cand] <= s) pid = cand;
    }
    const int poff   = s - pair_starts[pid];
    const bool pmask = poff < pair_lengths[pid];

    // ---- dtype sniff (wave-uniform) ----
    // 32-bit word #512 of pixels_pe:
    //   fp32 buffer: pe[1,0] = sin(1) = 0.84147  (0x3F576AA4)
    //   bf16 buffer: covers pe[2,0..1] -> 0xBED53F69 viewed as float = -0.4165
    union { uint32_t u; float f; } probe;
    probe.u = ((const uint32_t*)pixels_pe)[D_MODEL];
    const bool is_f32 = (probe.f > 0.82f && probe.f < 0.86f);

    const size_t bstride = (size_t)S_LEN * D_MODEL;   // elements per batch plane
    const size_t base    = (size_t)s * D_MODEL + d;

    if (is_f32) {
        // ---------------- float32 path ----------------
        const float* pxp = (const float*)pixels_pe + (size_t)pixrow   * D_MODEL + d;
        const float* gdp = (const float*)grids_pe  + (size_t)(gid & 1) * D_MODEL + d;
        const float* prp = (const float*)pairs_pe  + (size_t)pid      * D_MODEL + d;

        float comb[8];
        {
            float4 pxv0 = ((const float4*)pxp)[0], pxv1 = ((const float4*)pxp)[1];
            float4 gdv0 = ((const float4*)gdp)[0], gdv1 = ((const float4*)gdp)[1];
            float4 prv0 = ((const float4*)prp)[0], prv1 = ((const float4*)prp)[1];
            const float* px = (const float*)&pxv0;   // pxv0/pxv1 contiguous? no — handle separately
            const float* px1 = (const float*)&pxv1;
            const float* gd0 = (const float*)&gdv0, *gd1 = (const float*)&gdv1;
            const float* pr0 = (const float*)&prv0, *pr1 = (const float*)&prv1;
            #pragma unroll
            for (int j = 0; j < 4; ++j) {
                float a0 = gmask ? px[j]  : 0.0f;
                float g0 = gmask ? gd0[j] : 0.0f;
                float p0 = pmask ? pr0[j] : 0.0f;
                comb[j] = (a0 + g0) + p0;           // match reference associativity
                float a1 = gmask ? px1[j] : 0.0f;
                float g1 = gmask ? gd1[j] : 0.0f;
                float p1 = pmask ? pr1[j] : 0.0f;
                comb[4 + j] = (a1 + g1) + p1;
            }
        }

        const float* xf = (const float*)x;
        float*       of = (float*)out;

        // prefetch all 8 batch chunks (2x float4 each) for memory-level parallelism
        float4 xv[2 * B_SZ];
        #pragma unroll
        for (int b = 0; b < B_SZ; ++b) {
            const float4* p = (const float4*)(xf + base + (size_t)b * bstride);
            xv[2*b]     = p[0];
            xv[2*b + 1] = p[1];
        }
        #pragma unroll
        for (int b = 0; b < B_SZ; ++b) {
            float4 o0, o1;
            const float* xi0 = (const float*)&xv[2*b];
            const float* xi1 = (const float*)&xv[2*b + 1];
            float* o0f = (float*)&o0; float* o1f = (float*)&o1;
            #pragma unroll
            for (int j = 0; j < 4; ++j) {
                o0f[j] = xi0[j] + comb[j];
                o1f[j] = xi1[j] + comb[4 + j];
            }
            float4* op = (float4*)(of + base + (size_t)b * bstride);
            op[0] = o0;
            op[1] = o1;
        }
    } else {
        // ---------------- bf16 path ----------------
        const uint16_t* xh  = (const uint16_t*)x;
        uint16_t*       oh  = (uint16_t*)out;
        const uint4 pxv = *(const uint4*)((const uint16_t*)pixels_pe + (size_t)pixrow    * D_MODEL + d);
        const uint4 gdv = *(const uint4*)((const uint16_t*)grids_pe  + (size_t)(gid & 1) * D_MODEL + d);
        const uint4 prv = *(const uint4*)((const uint16_t*)pairs_pe  + (size_t)pid       * D_MODEL + d);
        const float gm = gmask ? 1.0f : 0.0f;
        const float pm = pmask ? 1.0f : 0.0f;

        float comb[8];
        {
            const uint32_t* px = (const uint32_t*)&pxv;
            const uint32_t* gd = (const uint32_t*)&gdv;
            const uint32_t* pr = (const uint32_t*)&prv;
            #pragma unroll
            for (int j = 0; j < 4; ++j) {
                float px_lo = bf16u_to_f32(px[j] & 0xFFFFu), px_hi = bf16u_to_f32(px[j] >> 16);
                float gd_lo = bf16u_to_f32(gd[j] & 0xFFFFu), gd_hi = bf16u_to_f32(gd[j] >> 16);
                float pr_lo = bf16u_to_f32(pr[j] & 0xFFFFu), pr_hi = bf16u_to_f32(pr[j] >> 16);
                comb[2*j]     = gm * (px_lo + gd_lo) + pm * pr_lo;
                comb[2*j + 1] = gm * (px_hi + gd_hi) + pm * pr_hi;
            }
        }

        uint4 xv[B_SZ];
        #pragma unroll
        for (int b = 0; b < B_SZ; ++b)
            xv[b] = *(const uint4*)(xh + base + (size_t)b * bstride);

        #pragma unroll
        for (int b = 0; b < B_SZ; ++b) {
            const uint32_t* xi = (const uint32_t*)&xv[b];
            uint4 ov;
            uint32_t* oi = (uint32_t*)&ov;
            #pragma unroll
            for (int j = 0; j < 4; ++j) {
                float lo = bf16u_to_f32(xi[j] & 0xFFFFu) + comb[2*j];
                float hi = bf16u_to_f32(xi[j] >> 16)     + comb[2*j + 1];
                oi[j] = pack2_bf16(lo, hi);
            }
            *(uint4*)(oh + base + (size_t)b * bstride) = ov;
        }
    }
}

extern "C" void kernel_launch(void* const* d_in, const int* in_sizes, int n_in,
                              void* d_out, int out_size, void* d_ws, size_t ws_size,
                              hipStream_t stream) {
    const void* x         = d_in[0];
    const void* pixels_pe = d_in[1];
    const void* grids_pe  = d_in[2];
    const void* pairs_pe  = d_in[3];
    const int* grid_starts  = (const int*)d_in[4];
    const int* grid_lengths = (const int*)d_in[5];
    const int* pair_starts  = (const int*)d_in[6];
    const int* pair_lengths = (const int*)d_in[7];

    const int threads = 256;
    const int blocks  = (TOTAL_CHUNKS + threads - 1) / threads;  // 4096
    hipLaunchKernelGGL(PositionalEncoding_30915174597069_kernel,
                       dim3(blocks), dim3(threads), 0, stream,
                       x, pixels_pe, grids_pe, pairs_pe,
                       grid_starts, grid_lengths, pair_starts, pair_lengths,
                       d_out);
}